// Round 3
// baseline (374.103 us; speedup 1.0000x reference)
//
#include <hip/hip_runtime.h>
#include <cstdint>

#define E_N   512
#define C_N   64
#define HW_N  784
#define CHW_N 50176     // C_N * HW_N
#define CHW4  12544     // CHW_N / 4
#define NC    256
#define NCOLS 401408    // E_N * HW_N

// ---------------- kernel 1: build corner->edge CSR + inv_count ----------------
// NOTE: harness delivers integer inputs as int32 (NOT int64) — reading them as
// long long was the round-2 crash (OOB reads + garbage indices -> GPU fault).
__global__ void build_adj_k(const int* __restrict__ ec,
                            int* __restrict__ adj_start,   // NC+1
                            int* __restrict__ adj_edge,    // 2*E_N
                            float* __restrict__ inv_count) // NC
{
    __shared__ int cnt[NC];
    __shared__ int st[NC + 1];
    int tid = threadIdx.x;
    if (tid < NC) cnt[tid] = 0;
    __syncthreads();
    for (int e = tid; e < E_N; e += 256) {
        int c0 = ec[2 * e]     & (NC - 1);   // defensive clamp (NC is pow2)
        int c1 = ec[2 * e + 1] & (NC - 1);
        atomicAdd(&cnt[c0], 1);
        atomicAdd(&cnt[c1], 1);
    }
    __syncthreads();
    if (tid == 0) {
        int s = 0;
        for (int c = 0; c < NC; ++c) { st[c] = s; s += cnt[c]; }
        st[NC] = s;
    }
    __syncthreads();
    if (tid < NC) {
        adj_start[tid] = st[tid];
        inv_count[tid] = 1.0f / (float)((cnt[tid] > 1) ? cnt[tid] : 1);
        cnt[tid] = st[tid];                 // reuse as cursor
    }
    if (tid == 0) adj_start[NC] = st[NC];
    __syncthreads();
    for (int e = tid; e < E_N; e += 256) {
        int c0 = ec[2 * e]     & (NC - 1);
        int c1 = ec[2 * e + 1] & (NC - 1);
        adj_edge[atomicAdd(&cnt[c0], 1)] = e;
        adj_edge[atomicAdd(&cnt[c1], 1)] = e;
    }
}

// ---------------- kernel 2: transpose first 192 cols of W_agg -> Wt[k][o] ----
__global__ void wt_k(const float* __restrict__ W, float* __restrict__ Wt)
{
    int i = blockIdx.x * 256 + threadIdx.x;   // 192*64 = 12288
    if (i < 192 * 64) {
        int k = i >> 6, o = i & 63;
        Wt[i] = W[o * 256 + k];
    }
}

// ---------------- kernel 3: global max over edges, partial (8 chunks), f4 ----
__global__ void gmax_part_k(const float* __restrict__ x, float* __restrict__ part)
{
    int p4 = blockIdx.x * 256 + threadIdx.x;   // 0..CHW4-1
    const float4* p = reinterpret_cast<const float4*>(x) + (size_t)(blockIdx.y * 64) * CHW4 + p4;
    float4 m = make_float4(-INFINITY, -INFINITY, -INFINITY, -INFINITY);
    #pragma unroll 4
    for (int i = 0; i < 64; ++i) {
        float4 v = p[(size_t)i * CHW4];
        m.x = fmaxf(m.x, v.x); m.y = fmaxf(m.y, v.y);
        m.z = fmaxf(m.z, v.z); m.w = fmaxf(m.w, v.w);
    }
    reinterpret_cast<float4*>(part)[blockIdx.y * CHW4 + p4] = m;
}

// ---------------- kernel 4: reduce the 8 partials (f4) -----------------------
__global__ void gmax_reduce_k(const float* __restrict__ part, float* __restrict__ gmax)
{
    int p4 = blockIdx.x * 256 + threadIdx.x;   // 0..CHW4-1
    const float4* p = reinterpret_cast<const float4*>(part);
    float4 m = p[p4];
    #pragma unroll
    for (int i = 1; i < 8; ++i) {
        float4 v = p[i * CHW4 + p4];
        m.x = fmaxf(m.x, v.x); m.y = fmaxf(m.y, v.y);
        m.z = fmaxf(m.z, v.z); m.w = fmaxf(m.w, v.w);
    }
    reinterpret_cast<float4*>(gmax)[p4] = m;
}

// ---------------- kernel 5: G4[o,hw] = sum_c W4[o,c]*gmax[c,hw] (f4) --------
__global__ void g4_k(const float* __restrict__ W, const float* __restrict__ gmax,
                     float* __restrict__ g4)
{
    int j4 = blockIdx.x * 256 + threadIdx.x;   // 0..CHW4-1 ; j = j4*4 = o*784+hw
    int o  = (j4 * 4) / HW_N;
    int hw = j4 * 4 - o * HW_N;                // multiple of 4
    float4 acc = make_float4(0.f, 0.f, 0.f, 0.f);
    #pragma unroll 8
    for (int c = 0; c < 64; ++c) {
        float w = W[o * 256 + 192 + c];
        float4 g = *reinterpret_cast<const float4*>(gmax + c * HW_N + hw);
        acc.x += w * g.x; acc.y += w * g.y; acc.z += w * g.z; acc.w += w * g.w;
    }
    *reinterpret_cast<float4*>(g4 + (size_t)j4 * 4) = acc;
}

// ---------------- kernel 6: corner features (segment mean) -------------------
__global__ void cf_k(const float* __restrict__ x, const int* __restrict__ adj_start,
                     const int* __restrict__ adj_edge, const float* __restrict__ inv_count,
                     float* __restrict__ cf)
{
    int c  = blockIdx.y;
    int p4 = blockIdx.x * 256 + threadIdx.x;  // float4 index in plane, 0..12543
    float4 acc = make_float4(0.f, 0.f, 0.f, 0.f);
    int s0 = adj_start[c], s1 = adj_start[c + 1];
    for (int i = s0; i < s1; ++i) {
        int e = adj_edge[i];
        float4 v = *reinterpret_cast<const float4*>(x + (size_t)e * CHW_N + (size_t)p4 * 4);
        acc.x += v.x; acc.y += v.y; acc.z += v.z; acc.w += v.w;
    }
    float ic = inv_count[c];
    acc.x *= ic; acc.y *= ic; acc.z *= ic; acc.w *= ic;
    *reinterpret_cast<float4*>(cf + (size_t)c * CHW_N + (size_t)p4 * 4) = acc;
}

// ---------------- kernel 7: fused K=192 matmul + G4 + relu -------------------
// out[o, j] = relu( sum_k Wt[k][o] * B[k][j] + G4[o, hw(j)] ),  j = e*784+hw
// B rows 0..63 = x[e], 64..127 = cf[c0(e)], 128..191 = cf[c1(e)]
__global__ __launch_bounds__(256) void fused_k(
    const float* __restrict__ x, const float* __restrict__ cf,
    const float* __restrict__ Wt, const float* __restrict__ g4,
    const int* __restrict__ ec, float* __restrict__ out)
{
    __shared__ float Bs[32][256];
    __shared__ float Ws[32][64];
    __shared__ int eArr[64];
    __shared__ int hwArr[64];
    __shared__ int base1[64];
    __shared__ int base2[64];

    int tid = threadIdx.x;
    int jbase = blockIdx.x * 256;

    if (tid < 64) {
        int j4 = jbase + tid * 4;
        int e  = j4 / HW_N;
        int hw = j4 - e * HW_N;             // multiple of 4 (784 % 4 == 0)
        eArr[tid]  = e;
        hwArr[tid] = hw;
        int c0 = ec[2 * e]     & (NC - 1);
        int c1 = ec[2 * e + 1] & (NC - 1);
        base1[tid] = c0 * CHW_N + hw;
        base2[tid] = c1 * CHW_N + hw;
    }

    float acc[8][8];
    #pragma unroll
    for (int i = 0; i < 8; ++i)
        #pragma unroll
        for (int j = 0; j < 8; ++j) acc[i][j] = 0.f;

    int o0 = (tid >> 5) << 3;   // 8 o-groups of 8
    int n0 = (tid & 31) << 2;   // 32 n-groups of 4 (plus +128 second block)

    for (int half = 0; half < 6; ++half) {
        __syncthreads();   // prev compute done reading Bs; eArr ready on iter 0
        int seg = half >> 1;            // 0:x  1:cf[c0]  2:cf[c1]
        int kr0 = (half & 1) * 32;
        // ---- stage B tile (32 rows x 256 cols) ----
        #pragma unroll
        for (int it = 0; it < 8; ++it) {
            int idx = it * 256 + tid;    // 0..2047
            int kk  = idx >> 6;          // 0..31
            int nq  = idx & 63;          // float4-group
            int kr  = kr0 + kk;
            const float* src;
            if (seg == 0)      src = x  + (size_t)eArr[nq] * CHW_N + kr * HW_N + hwArr[nq];
            else if (seg == 1) src = cf + (size_t)base1[nq] + kr * HW_N;
            else               src = cf + (size_t)base2[nq] + kr * HW_N;
            *reinterpret_cast<float4*>(&Bs[kk][nq * 4]) =
                *reinterpret_cast<const float4*>(src);
        }
        // ---- stage W tile (32 x 64), contiguous in Wt ----
        {
            const float4* wsrc = reinterpret_cast<const float4*>(Wt + (size_t)(seg * 64 + kr0) * 64);
            float4* wdst = reinterpret_cast<float4*>(&Ws[0][0]);
            wdst[tid]       = wsrc[tid];
            wdst[tid + 256] = wsrc[tid + 256];
        }
        __syncthreads();
        // ---- compute ----
        #pragma unroll 8
        for (int kk = 0; kk < 32; ++kk) {
            float4 xa = *reinterpret_cast<const float4*>(&Bs[kk][n0]);
            float4 xb = *reinterpret_cast<const float4*>(&Bs[kk][n0 + 128]);
            float4 wa = *reinterpret_cast<const float4*>(&Ws[kk][o0]);
            float4 wb = *reinterpret_cast<const float4*>(&Ws[kk][o0 + 4]);
            float xv[8] = {xa.x, xa.y, xa.z, xa.w, xb.x, xb.y, xb.z, xb.w};
            float wv[8] = {wa.x, wa.y, wa.z, wa.w, wb.x, wb.y, wb.z, wb.w};
            #pragma unroll
            for (int oi = 0; oi < 8; ++oi)
                #pragma unroll
                for (int ni = 0; ni < 8; ++ni)
                    acc[oi][ni] += wv[oi] * xv[ni];
        }
    }

    // ---- epilogue: + G4, relu, store ----
    #pragma unroll
    for (int oi = 0; oi < 8; ++oi) {
        int o = o0 + oi;
        #pragma unroll
        for (int nb = 0; nb < 2; ++nb) {
            int nq = (n0 + nb * 128) >> 2;
            int e  = eArr[nq];
            int hw = hwArr[nq];
            float4 g = *reinterpret_cast<const float4*>(g4 + o * HW_N + hw);
            float4 r;
            r.x = fmaxf(acc[oi][nb * 4 + 0] + g.x, 0.f);
            r.y = fmaxf(acc[oi][nb * 4 + 1] + g.y, 0.f);
            r.z = fmaxf(acc[oi][nb * 4 + 2] + g.z, 0.f);
            r.w = fmaxf(acc[oi][nb * 4 + 3] + g.w, 0.f);
            *reinterpret_cast<float4*>(out + (size_t)e * CHW_N + o * HW_N + hw) = r;
        }
    }
}

// ---------------- launch ----------------
extern "C" void kernel_launch(void* const* d_in, const int* in_sizes, int n_in,
                              void* d_out, int out_size, void* d_ws, size_t ws_size,
                              hipStream_t stream)
{
    const float* x  = (const float*)d_in[0];
    const float* W  = (const float*)d_in[1];
    const int*   ec = (const int*)d_in[3];    // edge_corner (E,2) — int32 per harness
    float* out      = (float*)d_out;

    // workspace layout (floats)
    float* ws_f      = (float*)d_ws;
    float* cf        = ws_f;                       // 12,845,056
    float* part      = cf + (size_t)NC * CHW_N;    // 401,408
    float* gmax      = part + 8 * CHW_N;           // 50,176
    float* g4        = gmax + CHW_N;               // 50,176
    float* wt        = g4 + CHW_N;                 // 12,288
    int*   adj_start = (int*)(wt + 12288);         // 257 (pad to 272)
    int*   adj_edge  = adj_start + 272;            // 1024
    float* inv_count = (float*)(adj_edge + 1024);  // 256

    build_adj_k<<<1, 256, 0, stream>>>(ec, adj_start, adj_edge, inv_count);
    wt_k<<<48, 256, 0, stream>>>(W, wt);
    gmax_part_k<<<dim3(49, 8), 256, 0, stream>>>(x, part);
    gmax_reduce_k<<<49, 256, 0, stream>>>(part, gmax);
    g4_k<<<49, 256, 0, stream>>>(W, gmax, g4);
    cf_k<<<dim3(49, NC), 256, 0, stream>>>(x, adj_start, adj_edge, inv_count, cf);
    fused_k<<<1568, 256, 0, stream>>>(x, cf, wt, g4, ec, out);
}